// Round 6
// baseline (723.053 us; speedup 1.0000x reference)
//
#include <hip/hip_runtime.h>
#include <cstdint>
#include <cstddef>

// ---------------------------------------------------------------------------
// AdaptiveLSTMCell (B=4096, I=1024, H=1024, AH=128, AI=16), fp32 in/out.
//   * big GEMMs via bf16 MFMA with 3-term hi/lo split:
//       C = Ahi*Whi + Ahi*Wlo + Alo*Whi  (K -> 3K virtual concat)
//     panels stored compact [hi|lo]; GEMM remaps K-tile pointer per-third.
//   * m97-style 128x128 tile GEMM, BK=32, global_load_lds(16B), XCD swizzle
//   * alpha/beta scaling + bias + per-row LN partial stats fused into the
//     XH/HH GEMM epilogue -> scale_stats kernel deleted (removes ~82us
//     LDS-issue + 256MB HBM round-trip). final_gates reduces partials.
//   * adaptive path fused per-row; zw/zb via pre-transposed weights
//   * ws total ~245.8 MB (must stay under ~256 MiB: R2 crashed at 262 MB)
// ---------------------------------------------------------------------------

#define B_   4096
#define I_   1024
#define H_   1024
#define AH_  128
#define G4_  4096   // 4*H
#define EPS_ 1e-5f

// out layout: hy (B*H) | new_total_h (B*1152) | new_total_c (B*1152)
#define OUT_TH ((size_t)B_ * H_)
#define OUT_TC (OUT_TH + (size_t)B_ * (H_ + AH_))

typedef short s16x8 __attribute__((ext_vector_type(8)));
typedef float f32x4 __attribute__((ext_vector_type(4)));

// ---------------- helpers ----------------
__device__ __forceinline__ unsigned short f2bf_rn(float f) {
    unsigned int u = __builtin_bit_cast(unsigned int, f);
    unsigned int r = u + 0x7FFFu + ((u >> 16) & 1u);   // round-to-nearest-even
    return (unsigned short)(r >> 16);
}
__device__ __forceinline__ float bf2f(unsigned short h) {
    unsigned int u = ((unsigned int)h) << 16;
    return __builtin_bit_cast(float, u);
}
__device__ __forceinline__ float sigf(float x) { return 1.0f / (1.0f + expf(-x)); }
__device__ __forceinline__ float dot4(f32x4 a, f32x4 b) {
    return a[0]*b[0] + a[1]*b[1] + a[2]*b[2] + a[3]*b[3];
}

__device__ __forceinline__ void gld16(const void* g, void* l) {
    __builtin_amdgcn_global_load_lds(
        (const __attribute__((address_space(1))) unsigned int*)g,
        (__attribute__((address_space(3))) unsigned int*)l,
        16, 0, 0);
}

// ---------------- split: fp32 -> bf16 [hi|lo] panel, 8 elems/thread --------
__global__ void split8_kernel(const float* __restrict__ src, int srcStride, int srcOff,
                              long nThreads, int kshift,
                              unsigned short* __restrict__ dst, int dstStride,
                              int offHi, int offLo) {
    long t = (long)blockIdx.x * blockDim.x + threadIdx.x;
    if (t >= nThreads) return;
    int r  = (int)(t >> kshift);
    int kk = ((int)t & ((1 << kshift) - 1)) * 8;
    const float* sp = src + (size_t)r * srcStride + srcOff + kk;
    f32x4 v0 = *(const f32x4*)sp;
    f32x4 v1 = *(const f32x4*)(sp + 4);
    float v[8] = {v0[0], v0[1], v0[2], v0[3], v1[0], v1[1], v1[2], v1[3]};
    s16x8 hi, lo;
#pragma unroll
    for (int j = 0; j < 8; ++j) {
        unsigned short hu = f2bf_rn(v[j]);
        unsigned short lu = f2bf_rn(v[j] - bf2f(hu));
        hi[j] = (short)hu; lo[j] = (short)lu;
    }
    size_t base = (size_t)r * dstStride + kk;
    *(s16x8*)(dst + base + offHi) = hi;
    *(s16x8*)(dst + base + offLo) = lo;
}

// ---------------- transpose 128x128 zw_w / zb_w (a-major for coalescing) ---
__global__ void transpose128_kernel(const float* __restrict__ zw_w, const float* __restrict__ zb_w,
                                    float* __restrict__ ZWT, float* __restrict__ ZBT) {
    int t = blockIdx.x * 256 + threadIdx.x;   // 16384
    int idx = t >> 7, a = t & 127;
    ZWT[a * 128 + idx] = zw_w[idx * 128 + a];
    ZBT[a * 128 + idx] = zb_w[idx * 128 + a];
}

// ---------------- GEMM: C(MxN) = A(MxK3) * W(NxK3)^T, bf16 in, fp32 out ----
// 3-term split: virtual K = 3*KA. A [hi|lo]: off = kt<kA1?kt:kt-kA1.
// W [hi|lo]: off = kt<kW1?kt:kt-kW1.
// blockIdx.z selects A0/A1 + W chunk + C slab.
// If PART != nullptr (fused mode, XH/HH): epilogue applies
//   v = acc*alpha + bias + beta  (alpha = zw[r]·aw[c], beta = zb[r]·bw[c])
// stores v, and writes per-row sum/sumsq partials (32-col granularity).
__launch_bounds__(256, 2)
__global__ void gemm_bt_bf16(const unsigned short* __restrict__ A0,
                             const unsigned short* __restrict__ A1,
                             int lda,
                             const unsigned short* __restrict__ W, int ldw, int wzOff,
                             float* __restrict__ C, int ldc, long czOff,
                             int K, int kA1, int kW1,
                             const float* __restrict__ ZW, const float* __restrict__ ZB,
                             const float* __restrict__ aw, const float* __restrict__ bw,
                             const float* __restrict__ biasX, const float* __restrict__ biasH,
                             float* __restrict__ PART) {
    __shared__ __align__(16) unsigned short As[128 * 32];
    __shared__ __align__(16) unsigned short Bs[128 * 32];
    const int z = blockIdx.z;
    const unsigned short* A  = z ? A1 : A0;
    const unsigned short* Wp = W + (size_t)z * wzOff;
    float* Cp = C + (size_t)z * czOff;

    // XCD-aware swizzle over x*y (all grids here have nwg % 8 == 0)
    const int gx = gridDim.x;
    int lin = blockIdx.y * gx + blockIdx.x;
    const int cpx = (gx * gridDim.y) >> 3;
    lin = (lin & 7) * cpx + (lin >> 3);
    const int bx = lin % gx, by = lin / gx;

    const int tid  = threadIdx.x;
    const int lane = tid & 63;
    const int w    = tid >> 6;           // wave 0..3
    const int wr   = w >> 1, wc = w & 1; // wave -> 64x64 quadrant
    const int l15  = lane & 15;
    const int lk   = (lane >> 4) * 8;
    const int rl   = (lane >> 4) * 4;

    f32x4 acc[4][4] = {};

    for (int kt = 0; kt < K; kt += 32) {
        const unsigned short* Ab = A  + (kt < kA1 ? kt : kt - kA1);
        const unsigned short* Wb = Wp + (kt < kW1 ? kt : kt - kW1);
#pragma unroll
        for (int it = 0; it < 2; ++it) {
            int q = it * 256 + tid;
            int row = q >> 2, c8 = (q & 3) * 8;
            gld16(Ab + (size_t)(by * 128 + row) * lda + c8,
                  (char*)As + (size_t)(it * 256 + w * 64) * 16);
        }
#pragma unroll
        for (int it = 0; it < 2; ++it) {
            int q = it * 256 + tid;
            int row = q >> 2, c8 = (q & 3) * 8;
            gld16(Wb + (size_t)(bx * 128 + row) * ldw + c8,
                  (char*)Bs + (size_t)(it * 256 + w * 64) * 16);
        }
        __syncthreads();

        s16x8 afr[4], bfr[4];
#pragma unroll
        for (int m = 0; m < 4; ++m)
            afr[m] = *(const s16x8*)&As[(wr * 64 + m * 16 + l15) * 32 + lk];
#pragma unroll
        for (int n = 0; n < 4; ++n)
            bfr[n] = *(const s16x8*)&Bs[(wc * 64 + n * 16 + l15) * 32 + lk];
#pragma unroll
        for (int m = 0; m < 4; ++m)
#pragma unroll
            for (int n = 0; n < 4; ++n)
                acc[m][n] = __builtin_amdgcn_mfma_f32_16x16x32_bf16(
                    afr[m], bfr[n], acc[m][n], 0, 0, 0);
        __syncthreads();
    }

    if (PART == nullptr) {
        // plain store (IG / HG partial GEMMs)
        const int r0 = by * 128 + wr * 64;
        const int c0 = bx * 128 + wc * 64;
#pragma unroll
        for (int m = 0; m < 4; ++m)
#pragma unroll
            for (int n = 0; n < 4; ++n)
#pragma unroll
                for (int j = 0; j < 4; ++j)
                    Cp[(size_t)(r0 + m * 16 + rl + j) * ldc + c0 + n * 16 + l15] = acc[m][n][j];
        return;
    }

    // ---------------- fused epilogue (XH / HH) ----------------
    const int se = (z ? 4 : 0) + (bx >> 3);        // s index 0..7 (uniform/block)
    float* zwl = (float*)As;                       // [128][16]
    float* zbl = (float*)Bs;
    {
        int rr = tid >> 1, ii = (tid & 1) * 8;
        const float* zp = ZW + (size_t)(by * 128 + rr) * 128 + se * 16 + ii;
        const float* yp = ZB + (size_t)(by * 128 + rr) * 128 + se * 16 + ii;
        f32x4 za = *(const f32x4*)zp, zc = *(const f32x4*)(zp + 4);
        f32x4 ya = *(const f32x4*)yp, yc = *(const f32x4*)(yp + 4);
        *(f32x4*)&zwl[rr * 16 + ii]     = za;
        *(f32x4*)&zwl[rr * 16 + ii + 4] = zc;
        *(f32x4*)&zbl[rr * 16 + ii]     = ya;
        *(f32x4*)&zbl[rr * 16 + ii + 4] = yc;
    }
    __syncthreads();

    const float* bias = z ? biasH : biasX;
#pragma unroll
    for (int half = 0; half < 2; ++half) {
        f32x4 awv[2][4], bwv[2][4];
        float bcv[2];
        int   ccol[2];
#pragma unroll
        for (int t = 0; t < 2; ++t) {
            int cc = bx * 128 + wc * 64 + (half * 2 + t) * 16 + l15;
            ccol[t] = cc;
            int h = cc & 1023;
            const f32x4* ap = (const f32x4*)(aw + ((size_t)se * 1024 + h) * 16);
            const f32x4* bp = (const f32x4*)(bw + ((size_t)se * 1024 + h) * 16);
            awv[t][0] = ap[0]; awv[t][1] = ap[1]; awv[t][2] = ap[2]; awv[t][3] = ap[3];
            bwv[t][0] = bp[0]; bwv[t][1] = bp[1]; bwv[t][2] = bp[2]; bwv[t][3] = bp[3];
            bcv[t] = bias[cc];
        }
#pragma unroll
        for (int m = 0; m < 4; ++m)
#pragma unroll
        for (int j = 0; j < 4; ++j) {
            const int rloc = wr * 64 + m * 16 + rl + j;
            const f32x4* zp = (const f32x4*)&zwl[rloc * 16];
            const f32x4* yp = (const f32x4*)&zbl[rloc * 16];
            f32x4 z0 = zp[0], z1 = zp[1], z2 = zp[2], z3 = zp[3];
            f32x4 y0 = yp[0], y1 = yp[1], y2 = yp[2], y3 = yp[3];
            float s = 0, q = 0;
#pragma unroll
            for (int t = 0; t < 2; ++t) {
                float alpha = dot4(z0, awv[t][0]) + dot4(z1, awv[t][1])
                            + dot4(z2, awv[t][2]) + dot4(z3, awv[t][3]);
                float beta  = dot4(y0, bwv[t][0]) + dot4(y1, bwv[t][1])
                            + dot4(y2, bwv[t][2]) + dot4(y3, bwv[t][3]);
                float v = acc[m][half * 2 + t][j] * alpha + bcv[t] + beta;
                Cp[(size_t)(by * 128 + rloc) * ldc + ccol[t]] = v;
                s += v; q += v * v;
            }
#pragma unroll
            for (int msk = 1; msk < 16; msk <<= 1) {
                s += __shfl_xor(s, msk); q += __shfl_xor(q, msk);
            }
            if (l15 == 0) {
                int cb = bx * 4 + wc * 2 + half;   // 0..127 (32-col granularity)
                float2 pr = { s, q };
                *(float2*)&PART[(((size_t)z * 4096 + by * 128 + rloc) * 128 + cb) * 2] = pr;
            }
        }
    }
}

// ---------------- adaptive path: LN(ig)+LN(hg) -> gates -> acy/ada -> zw/zb
// one wave per batch row; IG comes as two K-partials (IGa + IGb)
__launch_bounds__(64)
__global__ void adaptive_gates_kernel(const float* __restrict__ IGa, const float* __restrict__ IGb,
                                      const float* __restrict__ HG,
                                      const float* __restrict__ total_c,
                                      const float* __restrict__ alniw, const float* __restrict__ alnib,
                                      const float* __restrict__ alnhw, const float* __restrict__ alnhb,
                                      const float* __restrict__ alncw, const float* __restrict__ alncb,
                                      const float* __restrict__ ZWT, const float* __restrict__ zw_b,
                                      const float* __restrict__ ZBT,
                                      float* __restrict__ ZW, float* __restrict__ ZB,
                                      float* __restrict__ out) {
    const int b    = blockIdx.x;
    const int lane = threadIdx.x;
    __shared__ float ada_lds[AH_];

    float ig[8], hg[8];
    const float* ipa = IGa + (size_t)b * 512 + lane * 8;
    const float* ipb = IGb + (size_t)b * 512 + lane * 8;
    const float* hgp = HG  + (size_t)b * 512 + lane * 8;
    float sI = 0, qI = 0, sH = 0, qH = 0;
#pragma unroll
    for (int j = 0; j < 8; ++j) {
        ig[j] = ipa[j] + ipb[j]; sI += ig[j]; qI += ig[j] * ig[j];
        hg[j] = hgp[j];          sH += hg[j]; qH += hg[j] * hg[j];
    }
#pragma unroll
    for (int m = 1; m < 64; m <<= 1) {
        sI += __shfl_xor(sI, m); qI += __shfl_xor(qI, m);
        sH += __shfl_xor(sH, m); qH += __shfl_xor(qH, m);
    }
    const float muI = sI * (1.0f / 512.0f);
    const float rI  = rsqrtf(qI * (1.0f / 512.0f) - muI * muI + EPS_);
    const float muH = sH * (1.0f / 512.0f);
    const float rH  = rsqrtf(qH * (1.0f / 512.0f) - muH * muH + EPS_);

    float g[8];
#pragma unroll
    for (int j = 0; j < 8; ++j) {
        int c = lane * 8 + j;
        g[j] = (ig[j] - muI) * rI * alniw[c] + alnib[c]
             + (hg[j] - muH) * rH * alnhw[c] + alnhb[c];
    }

    // adaptive gate split order: gi, gf, gj, go (chunks 0..3 of 512)
    const int l15 = lane & 15;
    float cp[8], gov[8];
    float s = 0, q = 0;
#pragma unroll
    for (int j = 0; j < 8; ++j) {
        float giv = __shfl(g[j], l15);
        float gfv = __shfl(g[j], 16 + l15);
        float gjv = __shfl(g[j], 32 + l15);
        gov[j]    = __shfl(g[j], 48 + l15);
        int a = l15 * 8 + j;
        float ac = total_c[(size_t)b * (H_ + AH_) + H_ + a];
        cp[j] = sigf(gfv) * ac + sigf(giv) * tanhf(gjv);
        s += cp[j]; q += cp[j] * cp[j];
    }
#pragma unroll
    for (int m = 1; m < 16; m <<= 1) { s += __shfl_xor(s, m); q += __shfl_xor(q, m); }
    const float mu = s * (1.0f / 128.0f);
    const float rs = rsqrtf(q * (1.0f / 128.0f) - mu * mu + EPS_);

    float adav[8], acyv[8];
#pragma unroll
    for (int j = 0; j < 8; ++j) {
        int a = l15 * 8 + j;
        acyv[j] = (cp[j] - mu) * rs * alncw[a] + alncb[a];
        adav[j] = sigf(gov[j]) * tanhf(acyv[j]);
    }
    if (lane < 16) {
#pragma unroll
        for (int j = 0; j < 8; ++j) {
            int a = lane * 8 + j;
            ada_lds[a] = adav[j];
            out[OUT_TH + (size_t)b * (H_ + AH_) + H_ + a] = adav[j];  // ada
            out[OUT_TC + (size_t)b * (H_ + AH_) + H_ + a] = acyv[j]; // acy
        }
    }
    __syncthreads();

    // zw/zb: each lane produces outputs (2*lane, 2*lane+1); coalesced float2
    float az0 = 0, az1 = 0, ab0 = 0, ab1 = 0;
#pragma unroll 4
    for (int a = 0; a < 128; ++a) {
        float ad = ada_lds[a];                 // wave-uniform broadcast
        float2 wz = *(const float2*)&ZWT[a * 128 + lane * 2];
        float2 wb = *(const float2*)&ZBT[a * 128 + lane * 2];
        az0 += ad * wz.x; az1 += ad * wz.y;
        ab0 += ad * wb.x; ab1 += ad * wb.y;
    }
    const int i0 = lane * 2, i1 = lane * 2 + 1;
    ZW[(size_t)b * 128 + i0] = az0 + zw_b[i0];
    ZW[(size_t)b * 128 + i1] = az1 + zw_b[i1];
    ZB[(size_t)b * 128 + i0] = ab0;
    ZB[(size_t)b * 128 + i1] = ab1;
}

// ---------------- final: PART-reduce -> LN(in_g)+LN(hid_g) -> gates -> out -
__launch_bounds__(256)
__global__ void final_gates_kernel(const float* __restrict__ XH, const float* __restrict__ HH,
                                   const float* __restrict__ PART,
                                   const float* __restrict__ lniw, const float* __restrict__ lnib,
                                   const float* __restrict__ lnhw, const float* __restrict__ lnhb,
                                   const float* __restrict__ lncw, const float* __restrict__ lncb,
                                   const float* __restrict__ total_c,
                                   float* __restrict__ out) {
    const int b = blockIdx.x, tid = threadIdx.x;
    const int lane = tid & 63, w = tid >> 6;
    __shared__ float red[4][2];
    __shared__ float red2[2][2];   // [z][{S,Q}]

    // reduce PART partials for this row: waves 0 (z=0 / XH) and 1 (z=1 / HH)
    if (w < 2) {
        const float* pz = PART + ((size_t)w * 4096 + b) * 256;
        f32x4 v = *(const f32x4*)(pz + lane * 4);   // 2 cb entries {s,q,s,q}
        float s = v[0] + v[2], q = v[1] + v[3];
#pragma unroll
        for (int m = 1; m < 64; m <<= 1) { s += __shfl_xor(s, m); q += __shfl_xor(q, m); }
        if (lane == 0) { red2[w][0] = s; red2[w][1] = q; }
    }
    __syncthreads();
    const float muI = red2[0][0] * (1.0f / 4096.0f);
    const float rI  = rsqrtf(red2[0][1] * (1.0f / 4096.0f) - muI * muI + EPS_);
    const float muH = red2[1][0] * (1.0f / 4096.0f);
    const float rH  = rsqrtf(red2[1][1] * (1.0f / 4096.0f) - muH * muH + EPS_);

    const int h0 = tid * 4;
    float gg[4][4];
#pragma unroll
    for (int s = 0; s < 4; ++s) {
        int c = s * 1024 + h0;
        f32x4 xi = *(const f32x4*)(XH + (size_t)b * G4_ + c);
        f32x4 hi = *(const f32x4*)(HH + (size_t)b * G4_ + c);
        f32x4 wi = *(const f32x4*)(lniw + c);
        f32x4 bi = *(const f32x4*)(lnib + c);
        f32x4 wh = *(const f32x4*)(lnhw + c);
        f32x4 bh = *(const f32x4*)(lnhb + c);
#pragma unroll
        for (int e = 0; e < 4; ++e)
            gg[s][e] = (xi[e] - muI) * rI * wi[e] + bi[e]
                     + (hi[e] - muH) * rH * wh[e] + bh[e];
    }

    // main LSTM split order: i, j, f, o (chunks 0..3)
    float cp[4], ov[4];
    float s_ = 0, q_ = 0;
#pragma unroll
    for (int e = 0; e < 4; ++e) {
        float iv = gg[0][e], jv = gg[1][e], fv = gg[2][e];
        ov[e] = gg[3][e];
        float cx = total_c[(size_t)b * (H_ + AH_) + h0 + e];
        cp[e] = sigf(fv) * cx + sigf(iv) * tanhf(jv);
        s_ += cp[e]; q_ += cp[e] * cp[e];
    }
#pragma unroll
    for (int m = 1; m < 64; m <<= 1) { s_ += __shfl_xor(s_, m); q_ += __shfl_xor(q_, m); }
    if (lane == 0) { red[w][0] = s_; red[w][1] = q_; }
    __syncthreads();
    float S = red[0][0] + red[1][0] + red[2][0] + red[3][0];
    float Q = red[0][1] + red[1][1] + red[2][1] + red[3][1];
    float mu = S * (1.0f / 1024.0f);
    float rs = rsqrtf(Q * (1.0f / 1024.0f) - mu * mu + EPS_);

    f32x4 hyv, cyv;
#pragma unroll
    for (int e = 0; e < 4; ++e) {
        int h = h0 + e;
        float cy = (cp[e] - mu) * rs * lncw[h] + lncb[h];
        float hy = sigf(ov[e]) * tanhf(cy);
        cyv[e] = cy; hyv[e] = hy;
    }
    *(f32x4*)(out + (size_t)b * H_ + h0)                  = hyv;
    *(f32x4*)(out + OUT_TH + (size_t)b * (H_ + AH_) + h0) = hyv;
    *(f32x4*)(out + OUT_TC + (size_t)b * (H_ + AH_) + h0) = cyv;
}

// ---------------------------------------------------------------------------
extern "C" void kernel_launch(void* const* d_in, const int* in_sizes, int n_in,
                              void* d_out, int out_size, void* d_ws, size_t ws_size,
                              hipStream_t stream) {
    const float* x          = (const float*)d_in[0];
    const float* total_h    = (const float*)d_in[1];
    const float* total_c    = (const float*)d_in[2];
    const float* w_ih       = (const float*)d_in[3];
    const float* w_hh       = (const float*)d_in[4];
    const float* b_ih       = (const float*)d_in[5];
    const float* b_hh       = (const float*)d_in[6];
    const float* ln_i_w     = (const float*)d_in[7];
    const float* ln_i_b     = (const float*)d_in[8];
    const float* ln_h_w     = (const float*)d_in[9];
    const float* ln_h_b     = (const float*)d_in[10];
    const float* ln_c_w     = (const float*)d_in[11];
    const float* ln_c_b     = (const float*)d_in[12];
    const float* norm_zw_w  = (const float*)d_in[13];
    const float* norm_zw_b  = (const float*)d_in[14];
    const float* norm_alpha_w = (const float*)d_in[15];
    const float* bias_zb_w  = (const float*)d_in[16];
    const float* bias_beta_w = (const float*)d_in[17];
    const float* a_w_ih     = (const float*)d_in[18];
    const float* a_w_hh     = (const float*)d_in[19];
    const float* a_ln_i_w   = (const float*)d_in[20];
    const float* a_ln_i_b   = (const float*)d_in[21];
    const float* a_ln_h_w   = (const float*)d_in[22];
    const float* a_ln_h_b   = (const float*)d_in[23];
    const float* a_ln_c_w   = (const float*)d_in[24];
    const float* a_ln_c_b   = (const float*)d_in[25];
    float* out = (float*)d_out;

    // ws layout (bytes); total ~245.8 MB (keep < ~256 MiB, R2 crash lesson)
    char* ws = (char*)d_ws;
    unsigned short* XA  = (unsigned short*)(ws + 0);          // 4096x2048 [hi|lo]
    unsigned short* HXA = (unsigned short*)(ws + 16777216);   // 4096x2048
    unsigned short* WIH = (unsigned short*)(ws + 33554432);   // 4096x2048
    unsigned short* WHH = (unsigned short*)(ws + 50331648);   // 4096x2048
    unsigned short* WAI = (unsigned short*)(ws + 67108864);   // 512x4096
    unsigned short* AHS = (unsigned short*)(ws + 71303168);   // 4096x256
    unsigned short* WAH = (unsigned short*)(ws + 73400320);   // 512x256
    float* IG    = (float*)(ws + 73662464);                   // 2 x 4096x512
    float* HG    = (float*)(ws + 90439680);                   // 4096x512
    float* XHp   = (float*)(ws + 98828288);                   // 4096x4096
    float* HHp   = (float*)(ws + 165937152);                  // 4096x4096
    float* ZW    = (float*)(ws + 233046016);                  // 4096x128
    float* ZB    = (float*)(ws + 235143168);                  // 4096x128
    float* ZWT   = (float*)(ws + 237240320);                  // 128x128
    float* ZBT   = (float*)(ws + 237305856);                  // 128x128
    float* PART  = (float*)(ws + 237371392);                  // 2x4096x128x2

    auto grid8 = [](long n) { return dim3((unsigned)((n / 8 + 255) / 256)); };

    // ---- splits: [hi|lo] compact panels --------------------------------
    split8_kernel<<<grid8(4096L*1024), 256, 0, stream>>>(x,       1024, 0,    4096L*128, 7, XA,  2048, 0, 1024);
    split8_kernel<<<grid8(4096L*1024), 256, 0, stream>>>(total_h, 1152, 0,    4096L*128, 7, HXA, 2048, 0, 1024);
    split8_kernel<<<grid8(4096L*128),  256, 0, stream>>>(total_h, 1152, 1024, 4096L*16,  4, AHS, 256,  0, 128);
    split8_kernel<<<grid8(4096L*1024), 256, 0, stream>>>(w_ih,    1024, 0,    4096L*128, 7, WIH, 2048, 0, 1024);
    split8_kernel<<<grid8(4096L*1024), 256, 0, stream>>>(w_hh,    1024, 0,    4096L*128, 7, WHH, 2048, 0, 1024);
    split8_kernel<<<grid8(512L*1024),  256, 0, stream>>>(a_w_ih,  2048, 0,    512L*128,  7, WAI, 4096, 0,    1024);
    split8_kernel<<<grid8(512L*1024),  256, 0, stream>>>(a_w_ih,  2048, 1024, 512L*128,  7, WAI, 4096, 2048, 3072);
    split8_kernel<<<grid8(512L*128),   256, 0, stream>>>(a_w_hh,  128,  0,    512L*16,   4, WAH, 256,  0, 128);
    transpose128_kernel<<<64, 256, 0, stream>>>(norm_zw_w, bias_zb_w, ZWT, ZBT);

    // ---- small GEMMs (plain path, PART=nullptr) ------------------------
    // ig partials: z=0 -> x-part, z=1 -> hx-part (summed in adaptive_gates)
    gemm_bt_bf16<<<dim3(4, 32, 2), 256, 0, stream>>>(XA, HXA, 2048, WAI, 4096, 2048,
        IG, 512, 4096L*512, 3072, 1024, 2048,
        nullptr, nullptr, nullptr, nullptr, nullptr, nullptr, nullptr);
    // hg = ah @ a_w_hh.T
    gemm_bt_bf16<<<dim3(4, 32, 1), 256, 0, stream>>>(AHS, AHS, 256, WAH, 256, 0,
        HG, 512, 0, 384, 128, 256,
        nullptr, nullptr, nullptr, nullptr, nullptr, nullptr, nullptr);

    // ---- adaptive path: acy/ada (writes out tails) + zw/zb -------------
    adaptive_gates_kernel<<<4096, 64, 0, stream>>>(IG, IG + 4096L*512, HG, total_c,
        a_ln_i_w, a_ln_i_b, a_ln_h_w, a_ln_h_b, a_ln_c_w, a_ln_c_b,
        ZWT, norm_zw_b, ZBT, ZW, ZB, out);

    // ---- big GEMMs with fused alpha/beta + stats epilogue --------------
    // z=0: XH = x@w_ih.T ; z=1: HH = hx@w_hh.T   (WHH = WIH + 8388608 shorts)
    gemm_bt_bf16<<<dim3(32, 32, 2), 256, 0, stream>>>(XA, HXA, 2048, WIH, 2048, 8388608,
        XHp, 4096, 16777216, 3072, 1024, 2048,
        ZW, ZB, norm_alpha_w, bias_beta_w, b_ih, b_hh, PART);

    // ---- final gates + outputs -----------------------------------------
    final_gates_kernel<<<4096, 256, 0, stream>>>(XHp, HHp, PART,
        ln_i_w, ln_i_b, ln_h_w, ln_h_b, ln_c_w, ln_c_b, total_c, out);
}

// Round 7
// 687.787 us; speedup vs baseline: 1.0513x; 1.0513x over previous
//
#include <hip/hip_runtime.h>
#include <cstdint>
#include <cstddef>

// ---------------------------------------------------------------------------
// AdaptiveLSTMCell (B=4096, I=1024, H=1024, AH=128, AI=16), fp32 in/out.
//   * big GEMMs via bf16 MFMA, 3-term hi/lo split (C = AhiWhi+AhiWlo+AloWhi),
//     compact [hi|lo] panels, K-tile pointer remap. m97 128x128 tile, BK=32,
//     global_load_lds(16B), XCD swizzle. PLAIN STORE ONLY (R6 lesson: fusing
//     the alpha/beta epilogue into the GEMM cost 56->128 VGPR, occupancy
//     39.9->22.6%, MfmaUtil 36.8->22.7 => +150us. Keep GEMM lean.)
//   * prep (8 bf16 splits + zw/zb transpose) merged into ONE kernel
//     (compile-time segment table) -> 8 fewer launch gaps.
//   * scale_stats: 2 columns/lane => z/y ds_read_b128 count halved
//     (the R3 kernel's dominant cost: ~82us of LDS issue).
//   * adaptive path fused per-row; zw/zb via pre-transposed weights.
//   * ws ~226.5 MB (R2 lesson: stay under ~256 MiB).
// ---------------------------------------------------------------------------

#define B_   4096
#define I_   1024
#define H_   1024
#define AH_  128
#define G4_  4096   // 4*H
#define EPS_ 1e-5f

// out layout: hy (B*H) | new_total_h (B*1152) | new_total_c (B*1152)
#define OUT_TH ((size_t)B_ * H_)
#define OUT_TC (OUT_TH + (size_t)B_ * (H_ + AH_))

typedef short s16x8 __attribute__((ext_vector_type(8)));
typedef float f32x4 __attribute__((ext_vector_type(4)));

// ---------------- helpers ----------------
__device__ __forceinline__ unsigned short f2bf_rn(float f) {
    unsigned int u = __builtin_bit_cast(unsigned int, f);
    unsigned int r = u + 0x7FFFu + ((u >> 16) & 1u);   // round-to-nearest-even
    return (unsigned short)(r >> 16);
}
__device__ __forceinline__ float bf2f(unsigned short h) {
    unsigned int u = ((unsigned int)h) << 16;
    return __builtin_bit_cast(float, u);
}
__device__ __forceinline__ float sigf(float x) { return 1.0f / (1.0f + expf(-x)); }
__device__ __forceinline__ float dot4(f32x4 a, f32x4 b) {
    return a[0]*b[0] + a[1]*b[1] + a[2]*b[2] + a[3]*b[3];
}

__device__ __forceinline__ void gld16(const void* g, void* l) {
    __builtin_amdgcn_global_load_lds(
        (const __attribute__((address_space(1))) unsigned int*)g,
        (__attribute__((address_space(3))) unsigned int*)l,
        16, 0, 0);
}

// ---------------- prep: all splits + transpose in one launch ---------------
__device__ __forceinline__ void split_body(const float* __restrict__ src, int srcStride,
                                           int srcOff, int kshift,
                                           unsigned short* __restrict__ dst, int dstStride,
                                           int offHi, int offLo, int t) {
    int r  = t >> kshift;
    int kk = (t & ((1 << kshift) - 1)) * 8;
    const float* sp = src + (size_t)r * srcStride + srcOff + kk;
    f32x4 v0 = *(const f32x4*)sp;
    f32x4 v1 = *(const f32x4*)(sp + 4);
    float v[8] = {v0[0], v0[1], v0[2], v0[3], v1[0], v1[1], v1[2], v1[3]};
    s16x8 hi, lo;
#pragma unroll
    for (int j = 0; j < 8; ++j) {
        unsigned short hu = f2bf_rn(v[j]);
        unsigned short lu = f2bf_rn(v[j] - bf2f(hu));
        hi[j] = (short)hu; lo[j] = (short)lu;
    }
    size_t base = (size_t)r * dstStride + kk;
    *(s16x8*)(dst + base + offHi) = hi;
    *(s16x8*)(dst + base + offLo) = lo;
}

// grid = 9056 blocks x 256 threads; segment boundaries are compile-time.
__global__ void prep_kernel(const float* __restrict__ x, const float* __restrict__ total_h,
                            const float* __restrict__ w_ih, const float* __restrict__ w_hh,
                            const float* __restrict__ a_w_ih, const float* __restrict__ a_w_hh,
                            const float* __restrict__ zw_w, const float* __restrict__ zb_w,
                            unsigned short* __restrict__ XA, unsigned short* __restrict__ HXA,
                            unsigned short* __restrict__ WIH, unsigned short* __restrict__ WHH,
                            unsigned short* __restrict__ WAI, unsigned short* __restrict__ AHS,
                            unsigned short* __restrict__ WAH,
                            float* __restrict__ ZWT, float* __restrict__ ZBT) {
    const int bid = blockIdx.x, tid = threadIdx.x;
    if (bid < 2048) {
        split_body(x, 1024, 0, 7, XA, 2048, 0, 1024, bid * 256 + tid);
    } else if (bid < 4096) {
        split_body(total_h, 1152, 0, 7, HXA, 2048, 0, 1024, (bid - 2048) * 256 + tid);
    } else if (bid < 6144) {
        split_body(w_ih, 1024, 0, 7, WIH, 2048, 0, 1024, (bid - 4096) * 256 + tid);
    } else if (bid < 8192) {
        split_body(w_hh, 1024, 0, 7, WHH, 2048, 0, 1024, (bid - 6144) * 256 + tid);
    } else if (bid < 8448) {
        split_body(total_h, 1152, 1024, 4, AHS, 256, 0, 128, (bid - 8192) * 256 + tid);
    } else if (bid < 8704) {
        split_body(a_w_ih, 2048, 0, 7, WAI, 4096, 0, 1024, (bid - 8448) * 256 + tid);
    } else if (bid < 8960) {
        split_body(a_w_ih, 2048, 1024, 7, WAI, 4096, 2048, 3072, (bid - 8704) * 256 + tid);
    } else if (bid < 8992) {
        split_body(a_w_hh, 128, 0, 4, WAH, 256, 0, 128, (bid - 8960) * 256 + tid);
    } else {
        int t = (bid - 8992) * 256 + tid;      // 16384 threads
        int idx = t >> 7, a = t & 127;
        ZWT[a * 128 + idx] = zw_w[idx * 128 + a];
        ZBT[a * 128 + idx] = zb_w[idx * 128 + a];
    }
}

// ---------------- GEMM: C(MxN) = A(MxK3) * W(NxK3)^T, bf16 in, fp32 out ----
// 3-term split: virtual K = 3*KA. A [hi|lo]: off = kt<kA1?kt:kt-kA1.
// W [hi|lo]: off = kt<kW1?kt:kt-kW1.
// blockIdx.z selects A0/A1 + W chunk + C slab (K-split IG GEMM).
// (R3-proven form: 56 VGPR, plain store.)
__launch_bounds__(256, 2)
__global__ void gemm_bt_bf16(const unsigned short* __restrict__ A0,
                             const unsigned short* __restrict__ A1,
                             int lda,
                             const unsigned short* __restrict__ W, int ldw, int wzOff,
                             float* __restrict__ C, int ldc, long czOff,
                             int K, int kA1, int kW1) {
    __shared__ __align__(16) unsigned short As[128 * 32];
    __shared__ __align__(16) unsigned short Bs[128 * 32];
    const unsigned short* A  = blockIdx.z ? A1 : A0;
    const unsigned short* Wp = W + (size_t)blockIdx.z * wzOff;
    float* Cp = C + (size_t)blockIdx.z * czOff;

    // XCD-aware swizzle over x*y (all grids here have nwg % 8 == 0)
    const int gx = gridDim.x;
    int lin = blockIdx.y * gx + blockIdx.x;
    const int cpx = (gx * gridDim.y) >> 3;
    lin = (lin & 7) * cpx + (lin >> 3);
    const int bx = lin % gx, by = lin / gx;

    const int tid  = threadIdx.x;
    const int lane = tid & 63;
    const int w    = tid >> 6;           // wave 0..3
    const int wr   = w >> 1, wc = w & 1; // wave -> 64x64 quadrant
    const int l15  = lane & 15;
    const int lk   = (lane >> 4) * 8;

    f32x4 acc[4][4] = {};

    for (int kt = 0; kt < K; kt += 32) {
        const unsigned short* Ab = A  + (kt < kA1 ? kt : kt - kA1);
        const unsigned short* Wb = Wp + (kt < kW1 ? kt : kt - kW1);
#pragma unroll
        for (int it = 0; it < 2; ++it) {
            int q = it * 256 + tid;
            int row = q >> 2, c8 = (q & 3) * 8;
            gld16(Ab + (size_t)(by * 128 + row) * lda + c8,
                  (char*)As + (size_t)(it * 256 + w * 64) * 16);
        }
#pragma unroll
        for (int it = 0; it < 2; ++it) {
            int q = it * 256 + tid;
            int row = q >> 2, c8 = (q & 3) * 8;
            gld16(Wb + (size_t)(bx * 128 + row) * ldw + c8,
                  (char*)Bs + (size_t)(it * 256 + w * 64) * 16);
        }
        __syncthreads();

        s16x8 afr[4], bfr[4];
#pragma unroll
        for (int m = 0; m < 4; ++m)
            afr[m] = *(const s16x8*)&As[(wr * 64 + m * 16 + l15) * 32 + lk];
#pragma unroll
        for (int n = 0; n < 4; ++n)
            bfr[n] = *(const s16x8*)&Bs[(wc * 64 + n * 16 + l15) * 32 + lk];
#pragma unroll
        for (int m = 0; m < 4; ++m)
#pragma unroll
            for (int n = 0; n < 4; ++n)
                acc[m][n] = __builtin_amdgcn_mfma_f32_16x16x32_bf16(
                    afr[m], bfr[n], acc[m][n], 0, 0, 0);
        __syncthreads();
    }

    const int r0 = by * 128 + wr * 64;
    const int c0 = bx * 128 + wc * 64;
    const int rl = (lane >> 4) * 4;
#pragma unroll
    for (int m = 0; m < 4; ++m)
#pragma unroll
        for (int n = 0; n < 4; ++n)
#pragma unroll
            for (int j = 0; j < 4; ++j)
                Cp[(size_t)(r0 + m * 16 + rl + j) * ldc + c0 + n * 16 + l15] = acc[m][n][j];
}

// ---------------- adaptive path: LN(ig)+LN(hg) -> gates -> acy/ada -> zw/zb
// one wave per batch row; IG comes as two K-partials (IGa + IGb)
__launch_bounds__(64)
__global__ void adaptive_gates_kernel(const float* __restrict__ IGa, const float* __restrict__ IGb,
                                      const float* __restrict__ HG,
                                      const float* __restrict__ total_c,
                                      const float* __restrict__ alniw, const float* __restrict__ alnib,
                                      const float* __restrict__ alnhw, const float* __restrict__ alnhb,
                                      const float* __restrict__ alncw, const float* __restrict__ alncb,
                                      const float* __restrict__ ZWT, const float* __restrict__ zw_b,
                                      const float* __restrict__ ZBT,
                                      float* __restrict__ ZW, float* __restrict__ ZB,
                                      float* __restrict__ out) {
    const int b    = blockIdx.x;
    const int lane = threadIdx.x;
    __shared__ float ada_lds[AH_];

    float ig[8], hg[8];
    const float* ipa = IGa + (size_t)b * 512 + lane * 8;
    const float* ipb = IGb + (size_t)b * 512 + lane * 8;
    const float* hgp = HG  + (size_t)b * 512 + lane * 8;
    float sI = 0, qI = 0, sH = 0, qH = 0;
#pragma unroll
    for (int j = 0; j < 8; ++j) {
        ig[j] = ipa[j] + ipb[j]; sI += ig[j]; qI += ig[j] * ig[j];
        hg[j] = hgp[j];          sH += hg[j]; qH += hg[j] * hg[j];
    }
#pragma unroll
    for (int m = 1; m < 64; m <<= 1) {
        sI += __shfl_xor(sI, m); qI += __shfl_xor(qI, m);
        sH += __shfl_xor(sH, m); qH += __shfl_xor(qH, m);
    }
    const float muI = sI * (1.0f / 512.0f);
    const float rI  = rsqrtf(qI * (1.0f / 512.0f) - muI * muI + EPS_);
    const float muH = sH * (1.0f / 512.0f);
    const float rH  = rsqrtf(qH * (1.0f / 512.0f) - muH * muH + EPS_);

    float g[8];
#pragma unroll
    for (int j = 0; j < 8; ++j) {
        int c = lane * 8 + j;
        g[j] = (ig[j] - muI) * rI * alniw[c] + alnib[c]
             + (hg[j] - muH) * rH * alnhw[c] + alnhb[c];
    }

    // adaptive gate split order: gi, gf, gj, go (chunks 0..3 of 512)
    const int l15 = lane & 15;
    float cp[8], gov[8];
    float s = 0, q = 0;
#pragma unroll
    for (int j = 0; j < 8; ++j) {
        float giv = __shfl(g[j], l15);
        float gfv = __shfl(g[j], 16 + l15);
        float gjv = __shfl(g[j], 32 + l15);
        gov[j]    = __shfl(g[j], 48 + l15);
        int a = l15 * 8 + j;
        float ac = total_c[(size_t)b * (H_ + AH_) + H_ + a];
        cp[j] = sigf(gfv) * ac + sigf(giv) * tanhf(gjv);
        s += cp[j]; q += cp[j] * cp[j];
    }
#pragma unroll
    for (int m = 1; m < 16; m <<= 1) { s += __shfl_xor(s, m); q += __shfl_xor(q, m); }
    const float mu = s * (1.0f / 128.0f);
    const float rs = rsqrtf(q * (1.0f / 128.0f) - mu * mu + EPS_);

    float adav[8], acyv[8];
#pragma unroll
    for (int j = 0; j < 8; ++j) {
        int a = l15 * 8 + j;
        acyv[j] = (cp[j] - mu) * rs * alncw[a] + alncb[a];
        adav[j] = sigf(gov[j]) * tanhf(acyv[j]);
    }
    if (lane < 16) {
#pragma unroll
        for (int j = 0; j < 8; ++j) {
            int a = lane * 8 + j;
            ada_lds[a] = adav[j];
            out[OUT_TH + (size_t)b * (H_ + AH_) + H_ + a] = adav[j];  // ada
            out[OUT_TC + (size_t)b * (H_ + AH_) + H_ + a] = acyv[j]; // acy
        }
    }
    __syncthreads();

    // zw/zb: each lane produces outputs (2*lane, 2*lane+1); coalesced float2
    float az0 = 0, az1 = 0, ab0 = 0, ab1 = 0;
#pragma unroll 4
    for (int a = 0; a < 128; ++a) {
        float ad = ada_lds[a];                 // wave-uniform broadcast
        float2 wz = *(const float2*)&ZWT[a * 128 + lane * 2];
        float2 wb = *(const float2*)&ZBT[a * 128 + lane * 2];
        az0 += ad * wz.x; az1 += ad * wz.y;
        ab0 += ad * wb.x; ab1 += ad * wb.y;
    }
    const int i0 = lane * 2, i1 = lane * 2 + 1;
    ZW[(size_t)b * 128 + i0] = az0 + zw_b[i0];
    ZW[(size_t)b * 128 + i1] = az1 + zw_b[i1];
    ZB[(size_t)b * 128 + i0] = ab0;
    ZB[(size_t)b * 128 + i1] = ab1;
}

// ---------------- scale xh/hh by alpha,+bias+beta (in place) + row stats ---
// 8 rows/block; 2 columns per lane => z/y LDS b128 reads amortized 2x
// (R3's dominant cost: 1024 b128/thread ~= 82us of LDS issue; now 512).
__launch_bounds__(512, 1)
__global__ void scale_stats_kernel(float* __restrict__ XH, float* __restrict__ HH,
                                   const float* __restrict__ ZW, const float* __restrict__ ZB,
                                   const float* __restrict__ aw, const float* __restrict__ bw,
                                   const float* __restrict__ b_ih, const float* __restrict__ b_hh,
                                   float* __restrict__ STATS) {
    const int tid  = threadIdx.x;
    const int lane = tid & 63;
    const int w    = tid >> 6;     // 8 waves
    const int b0   = blockIdx.x * 8;

    __shared__ __align__(16) float zwl[8 * 128], zbl[8 * 128];
    __shared__ float part[8][8][4];
    __shared__ float tot[8][4];

    for (int t = tid; t < 1024; t += 512) {
        int r = t >> 7, si = t & 127;
        zwl[t] = ZW[(size_t)(b0 + r) * 128 + si];
        zbl[t] = ZB[(size_t)(b0 + r) * 128 + si];
    }
    __syncthreads();

    float sI[8] = {}, qI[8] = {}, sH[8] = {}, qH[8] = {};

    for (int strip = w; strip < 64; strip += 8) {   // 32 in_g strips, 32 hid_g (128 cols each)
        const bool isIn = strip < 32;
        const int  c    = (isIn ? strip : strip - 32) * 128 + lane * 2;  // even col 0..4094
        const int  se   = (c >> 10) + (isIn ? 0 : 4);                    // s index 0..7
        float*       X    = isIn ? XH : HH;
        const float* bias = isIn ? b_ih : b_hh;
        const int    h    = c & 1023;

        // weights for cols c (A[0..3]) and c+1 (A[4..7]) - contiguous 8 f32x4
        const f32x4* ap = (const f32x4*)(aw + ((size_t)se * 1024 + h) * 16);
        const f32x4* bp = (const f32x4*)(bw + ((size_t)se * 1024 + h) * 16);
        f32x4 A0 = ap[0], A1 = ap[1], A2 = ap[2], A3 = ap[3];
        f32x4 A4 = ap[4], A5 = ap[5], A6 = ap[6], A7 = ap[7];
        f32x4 B0 = bp[0], B1 = bp[1], B2 = bp[2], B3 = bp[3];
        f32x4 B4 = bp[4], B5 = bp[5], B6 = bp[6], B7 = bp[7];
        const float2 bc = *(const float2*)&bias[c];

#pragma unroll
        for (int r = 0; r < 8; ++r) {
            const f32x4* zp = (const f32x4*)&zwl[r * 128 + se * 16];
            const f32x4* yp = (const f32x4*)&zbl[r * 128 + se * 16];
            f32x4 z0 = zp[0], z1 = zp[1], z2 = zp[2], z3 = zp[3];
            f32x4 y0 = yp[0], y1 = yp[1], y2 = yp[2], y3 = yp[3];
            float alpha0 = dot4(z0, A0) + dot4(z1, A1) + dot4(z2, A2) + dot4(z3, A3);
            float alpha1 = dot4(z0, A4) + dot4(z1, A5) + dot4(z2, A6) + dot4(z3, A7);
            float beta0  = dot4(y0, B0) + dot4(y1, B1) + dot4(y2, B2) + dot4(y3, B3);
            float beta1  = dot4(y0, B4) + dot4(y1, B5) + dot4(y2, B6) + dot4(y3, B7);
            size_t off = (size_t)(b0 + r) * G4_ + c;
            float2 xv = *(const float2*)&X[off];
            float v0 = xv.x * alpha0 + bc.x + beta0;
            float v1 = xv.y * alpha1 + bc.y + beta1;
            float2 vv = { v0, v1 };
            *(float2*)&X[off] = vv;
            float sv = v0 + v1, qv = v0 * v0 + v1 * v1;
            if (isIn) { sI[r] += sv; qI[r] += qv; }
            else      { sH[r] += sv; qH[r] += qv; }
        }
    }

#pragma unroll
    for (int r = 0; r < 8; ++r) {
#pragma unroll
        for (int m = 1; m < 64; m <<= 1) {
            sI[r] += __shfl_xor(sI[r], m); qI[r] += __shfl_xor(qI[r], m);
            sH[r] += __shfl_xor(sH[r], m); qH[r] += __shfl_xor(qH[r], m);
        }
        if (lane == 0) {
            part[w][r][0] = sI[r]; part[w][r][1] = qI[r];
            part[w][r][2] = sH[r]; part[w][r][3] = qH[r];
        }
    }
    __syncthreads();
    if (tid < 32) {
        int r = tid >> 2, cmp = tid & 3;
        float t = 0;
        for (int ww = 0; ww < 8; ++ww) t += part[ww][r][cmp];
        tot[r][cmp] = t;
    }
    __syncthreads();
    if (tid < 8) {
        int r = tid;
        float muI = tot[r][0] * (1.0f / 4096.0f);
        float vI  = tot[r][1] * (1.0f / 4096.0f) - muI * muI;
        float muH = tot[r][2] * (1.0f / 4096.0f);
        float vH  = tot[r][3] * (1.0f / 4096.0f) - muH * muH;
        f32x4 st = { muI, rsqrtf(vI + EPS_), muH, rsqrtf(vH + EPS_) };
        *(f32x4*)(STATS + (size_t)(b0 + r) * 4) = st;
    }
}

// ---------------- final: LN(in_g)+LN(hid_g) -> LSTM gates -> LN(c) -> out --
__launch_bounds__(256)
__global__ void final_gates_kernel(const float* __restrict__ XH, const float* __restrict__ HH,
                                   const float* __restrict__ STATS,
                                   const float* __restrict__ lniw, const float* __restrict__ lnib,
                                   const float* __restrict__ lnhw, const float* __restrict__ lnhb,
                                   const float* __restrict__ lncw, const float* __restrict__ lncb,
                                   const float* __restrict__ total_c,
                                   float* __restrict__ out) {
    const int b = blockIdx.x, tid = threadIdx.x;
    const int lane = tid & 63, w = tid >> 6;
    __shared__ float red[4][2];

    const f32x4 st = *(const f32x4*)(STATS + (size_t)b * 4); // muI,rI,muH,rH
    const int h0 = tid * 4;

    float gg[4][4];
#pragma unroll
    for (int s = 0; s < 4; ++s) {
        int c = s * 1024 + h0;
        f32x4 xi = *(const f32x4*)(XH + (size_t)b * G4_ + c);
        f32x4 hi = *(const f32x4*)(HH + (size_t)b * G4_ + c);
        f32x4 wi = *(const f32x4*)(lniw + c);
        f32x4 bi = *(const f32x4*)(lnib + c);
        f32x4 wh = *(const f32x4*)(lnhw + c);
        f32x4 bh = *(const f32x4*)(lnhb + c);
#pragma unroll
        for (int e = 0; e < 4; ++e)
            gg[s][e] = (xi[e] - st[0]) * st[1] * wi[e] + bi[e]
                     + (hi[e] - st[2]) * st[3] * wh[e] + bh[e];
    }

    // main LSTM split order: i, j, f, o (chunks 0..3)
    float cp[4], ov[4];
    float s_ = 0, q_ = 0;
#pragma unroll
    for (int e = 0; e < 4; ++e) {
        float iv = gg[0][e], jv = gg[1][e], fv = gg[2][e];
        ov[e] = gg[3][e];
        float cx = total_c[(size_t)b * (H_ + AH_) + h0 + e];
        cp[e] = sigf(fv) * cx + sigf(iv) * tanhf(jv);
        s_ += cp[e]; q_ += cp[e] * cp[e];
    }
#pragma unroll
    for (int m = 1; m < 64; m <<= 1) { s_ += __shfl_xor(s_, m); q_ += __shfl_xor(q_, m); }
    if (lane == 0) { red[w][0] = s_; red[w][1] = q_; }
    __syncthreads();
    float S = red[0][0] + red[1][0] + red[2][0] + red[3][0];
    float Q = red[0][1] + red[1][1] + red[2][1] + red[3][1];
    float mu = S * (1.0f / 1024.0f);
    float rs = rsqrtf(Q * (1.0f / 1024.0f) - mu * mu + EPS_);

    f32x4 hyv, cyv;
#pragma unroll
    for (int e = 0; e < 4; ++e) {
        int h = h0 + e;
        float cy = (cp[e] - mu) * rs * lncw[h] + lncb[h];
        float hy = sigf(ov[e]) * tanhf(cy);
        cyv[e] = cy; hyv[e] = hy;
    }
    *(f32x4*)(out + (size_t)b * H_ + h0)                  = hyv;
    *(f32x4*)(out + OUT_TH + (size_t)b * (H_ + AH_) + h0) = hyv;
    *(f32x4*)(out + OUT_TC + (size_t)b * (H_ + AH_) + h0) = cyv;
}

// ---------------------------------------------------------------------------
extern "C" void kernel_launch(void* const* d_in, const int* in_sizes, int n_in,
                              void* d_out, int out_size, void* d_ws, size_t ws_size,
                              hipStream_t stream) {
    const float* x          = (const float*)d_in[0];
    const float* total_h    = (const float*)d_in[1];
    const float* total_c    = (const float*)d_in[2];
    const float* w_ih       = (const float*)d_in[3];
    const float* w_hh       = (const float*)d_in[4];
    const float* b_ih       = (const float*)d_in[5];
    const float* b_hh       = (const float*)d_in[6];
    const float* ln_i_w     = (const float*)d_in[7];
    const float* ln_i_b     = (const float*)d_in[8];
    const float* ln_h_w     = (const float*)d_in[9];
    const float* ln_h_b     = (const float*)d_in[10];
    const float* ln_c_w     = (const float*)d_in[11];
    const float* ln_c_b     = (const float*)d_in[12];
    const float* norm_zw_w  = (const float*)d_in[13];
    const float* norm_zw_b  = (const float*)d_in[14];
    const float* norm_alpha_w = (const float*)d_in[15];
    const float* bias_zb_w  = (const float*)d_in[16];
    const float* bias_beta_w = (const float*)d_in[17];
    const float* a_w_ih     = (const float*)d_in[18];
    const float* a_w_hh     = (const float*)d_in[19];
    const float* a_ln_i_w   = (const float*)d_in[20];
    const float* a_ln_i_b   = (const float*)d_in[21];
    const float* a_ln_h_w   = (const float*)d_in[22];
    const float* a_ln_h_b   = (const float*)d_in[23];
    const float* a_ln_c_w   = (const float*)d_in[24];
    const float* a_ln_c_b   = (const float*)d_in[25];
    float* out = (float*)d_out;

    // ws layout (bytes); total ~226.5 MB (keep < ~256 MiB, R2 crash lesson)
    char* ws = (char*)d_ws;
    unsigned short* XA  = (unsigned short*)(ws + 0);          // 4096x2048 [hi|lo]
    unsigned short* HXA = (unsigned short*)(ws + 16777216);   // 4096x2048
    unsigned short* WIH = (unsigned short*)(ws + 33554432);   // 4096x2048
    unsigned short* WHH = (unsigned short*)(ws + 50331648);   // 4096x2048
    unsigned short* WAI = (unsigned short*)(ws + 67108864);   // 512x4096
    unsigned short* AHS = (unsigned short*)(ws + 71303168);   // 4096x256
    unsigned short* WAH = (unsigned short*)(ws + 73400320);   // 512x256
    float* IG    = (float*)(ws + 73662464);                   // 2 x 4096x512
    float* HG    = (float*)(ws + 90439680);                   // 4096x512
    float* XHp   = (float*)(ws + 98828288);                   // 4096x4096
    float* HHp   = (float*)(ws + 165937152);                  // 4096x4096
    float* ZW    = (float*)(ws + 233046016);                  // 4096x128
    float* ZB    = (float*)(ws + 235143168);                  // 4096x128
    float* STATS = (float*)(ws + 237240320);                  // 4096x4
    float* ZWT   = (float*)(ws + 237305856);                  // 128x128
    float* ZBT   = (float*)(ws + 237371392);                  // 128x128

    // ---- prep: all 8 splits + transpose, one launch --------------------
    prep_kernel<<<9056, 256, 0, stream>>>(x, total_h, w_ih, w_hh, a_w_ih, a_w_hh,
        norm_zw_w, bias_zb_w, XA, HXA, WIH, WHH, WAI, AHS, WAH, ZWT, ZBT);

    // ---- small GEMMs ----------------------------------------------------
    // ig partials: z=0 -> x-part, z=1 -> hx-part (summed in adaptive_gates)
    gemm_bt_bf16<<<dim3(4, 32, 2), 256, 0, stream>>>(XA, HXA, 2048, WAI, 4096, 2048,
        IG, 512, 4096L*512, 3072, 1024, 2048);
    // hg = ah @ a_w_hh.T
    gemm_bt_bf16<<<dim3(4, 32, 1), 256, 0, stream>>>(AHS, AHS, 256, WAH, 256, 0,
        HG, 512, 0, 384, 128, 256);

    // ---- adaptive path: acy/ada (writes out tails) + zw/zb -------------
    adaptive_gates_kernel<<<4096, 64, 0, stream>>>(IG, IG + 4096L*512, HG, total_c,
        a_ln_i_w, a_ln_i_b, a_ln_h_w, a_ln_h_b, a_ln_c_w, a_ln_c_b,
        ZWT, norm_zw_b, ZBT, ZW, ZB, out);

    // ---- big GEMMs (plain store, R3-proven 56-VGPR form) ---------------
    gemm_bt_bf16<<<dim3(32, 32, 1), 256, 0, stream>>>(XA,  XA,  2048, WIH, 2048, 0,
        XHp, 4096, 0, 3072, 1024, 2048);
    gemm_bt_bf16<<<dim3(32, 32, 1), 256, 0, stream>>>(HXA, HXA, 2048, WHH, 2048, 0,
        HHp, 4096, 0, 3072, 1024, 2048);

    // ---- alpha/beta scale (in place) + LN4096 stats --------------------
    scale_stats_kernel<<<512, 512, 0, stream>>>(XHp, HHp, ZW, ZB,
        norm_alpha_w, bias_beta_w, b_ih, b_hh, STATS);

    // ---- final gates + outputs -----------------------------------------
    final_gates_kernel<<<4096, 256, 0, stream>>>(XHp, HHp, STATS,
        ln_i_w, ln_i_b, ln_h_w, ln_h_b, ln_c_w, ln_c_b, total_c, out);
}